// Round 2
// baseline (331.643 us; speedup 1.0000x reference)
//
#include <hip/hip_runtime.h>

// B=256, T=256, C=512, H=64. Inputs fp32; compute f16 MFMA, fp32 accum.
// ws layout: q | k | v (each 65536x64 f16, 8,388,608 B) then packed-W
// (3 x 65,536 B). Total ws use = 25,362,432 B.

typedef _Float16 half8 __attribute__((ext_vector_type(8)));
typedef float floatx4 __attribute__((ext_vector_type(4)));

#define MFMA16(a, b, c) __builtin_amdgcn_mfma_f32_16x16x32_f16((a), (b), (c), 0, 0, 0)

__device__ inline half8 cvt8(float4 a, float4 b) {
  half8 r;
  r[0] = (_Float16)a.x; r[1] = (_Float16)a.y; r[2] = (_Float16)a.z; r[3] = (_Float16)a.w;
  r[4] = (_Float16)b.x; r[5] = (_Float16)b.y; r[6] = (_Float16)b.z; r[7] = (_Float16)b.w;
  return r;
}

// ---- prep: pack W fp32 [512][64] -> f16 per-lane MFMA B-frag layout ----
// pack[w][kk*4+j][lane][e] = W_w[kk*32 + (lane>>4)*8 + e][j*16 + (lane&15)]
__global__ __launch_bounds__(256) void pack_kernel(
    const float* __restrict__ Wq, const float* __restrict__ Wk,
    const float* __restrict__ Wv, _Float16* __restrict__ P) {
  const int kk = blockIdx.x;          // 0..15
  const int w = blockIdx.y;           // 0..2
  const float* W = (w == 0) ? Wq : ((w == 1) ? Wk : Wv);
  const int tid = threadIdx.x;
  const int lane = tid & 63, j = tid >> 6;
  const int l15 = lane & 15, quad = lane >> 4;
  half8 h;
#pragma unroll
  for (int e = 0; e < 8; e++)
    h[e] = (_Float16)W[(size_t)(kk * 32 + quad * 8 + e) * 64 + j * 16 + l15];
  *(half8*)(P + (size_t)w * 32768 + (size_t)((kk * 4 + j) * 64 + lane) * 8) = h;
}

// ---- proj: barrier-free streaming GEMM ----
// blocks 0..1023: q = x*Wq (64 rows each). blocks 1024..2047: k,v from y.
// Wave owns 16 rows; A-frags direct from global (fp32->f16), B-frags from
// packed W (16B/lane contiguous, L1/L2-hot).
__global__ __launch_bounds__(256, 4) void proj_kernel(
    const float* __restrict__ X, const float* __restrict__ Y,
    const _Float16* __restrict__ Pw, _Float16* __restrict__ Q,
    _Float16* __restrict__ K, _Float16* __restrict__ V) {
  const int b = blockIdx.x;
  const int tid = threadIdx.x;
  const int wv = tid >> 6, lane = tid & 63;
  const int l15 = lane & 15, quad = lane >> 4;
  const half8* WP = (const half8*)Pw;  // per-W stride 4096 frags

  if (b < 1024) {
    const int row0 = b * 64;
    const float* A = X + (size_t)(row0 + wv * 16 + l15) * 512 + quad * 8;
    floatx4 acc[4];
#pragma unroll
    for (int j = 0; j < 4; j++) acc[j] = (floatx4)0.f;
#pragma unroll
    for (int kk = 0; kk < 16; kk++) {
      float4 a0 = *(const float4*)(A + kk * 32);
      float4 a1 = *(const float4*)(A + kk * 32 + 4);
      half8 af = cvt8(a0, a1);
#pragma unroll
      for (int j = 0; j < 4; j++) {
        half8 bf = WP[(kk * 4 + j) * 64 + lane];
        acc[j] = MFMA16(af, bf, acc[j]);
      }
    }
#pragma unroll
    for (int j = 0; j < 4; j++)
#pragma unroll
      for (int r = 0; r < 4; r++)
        Q[(size_t)(row0 + wv * 16 + quad * 4 + r) * 64 + j * 16 + l15] =
            (_Float16)acc[j][r];
  } else {
    const int row0 = (b - 1024) * 64;
    const float* A = Y + (size_t)(row0 + wv * 16 + l15) * 512 + quad * 8;
    floatx4 acck[4], accv[4];
#pragma unroll
    for (int j = 0; j < 4; j++) { acck[j] = (floatx4)0.f; accv[j] = (floatx4)0.f; }
#pragma unroll
    for (int kk = 0; kk < 16; kk++) {
      float4 a0 = *(const float4*)(A + kk * 32);
      float4 a1 = *(const float4*)(A + kk * 32 + 4);
      half8 af = cvt8(a0, a1);
#pragma unroll
      for (int j = 0; j < 4; j++) {
        half8 bk = WP[4096 + (kk * 4 + j) * 64 + lane];
        acck[j] = MFMA16(af, bk, acck[j]);
        half8 bv = WP[8192 + (kk * 4 + j) * 64 + lane];
        accv[j] = MFMA16(af, bv, accv[j]);
      }
    }
#pragma unroll
    for (int j = 0; j < 4; j++)
#pragma unroll
      for (int r = 0; r < 4; r++) {
        const size_t o = (size_t)(row0 + wv * 16 + quad * 4 + r) * 64 + j * 16 + l15;
        K[o] = (_Float16)acck[j][r];
        V[o] = (_Float16)accv[j][r];
      }
  }
}

// ---- flash attention, causal. Grid (qt=4, b=256); block 256 = 4 waves. ----
__global__ __launch_bounds__(256) void attn_kernel(
    const _Float16* __restrict__ Qw, const _Float16* __restrict__ Kw,
    const _Float16* __restrict__ Vw, float* __restrict__ Out) {
  __shared__ _Float16 k_lds[64][72];       // [s][h]
  __shared__ _Float16 vt_lds[64][72];      // [h][s] (V transposed)
  __shared__ _Float16 p_lds[4][16][72];    // per-wave (private) P round-trip

  const int qt = blockIdx.x, bb = blockIdx.y;
  const int tid = threadIdx.x;
  const int wv = tid >> 6;
  const int lane = tid & 63;
  const int l15 = lane & 15, quad = lane >> 4;
  const float NEG = -3.0e38f;
  const _Float16 SCALE = (_Float16)(0.125f * 1.4426950408889634f);  // /sqrt(64)*log2e

  // Q fragments (A layout: m=l15, k=quad*8+e), pre-scaled so S is in exp2 domain
  const size_t qoff = ((size_t)bb * 256 + qt * 64 + wv * 16 + l15) * 64 + quad * 8;
  half8 qf0 = *(const half8*)(Qw + qoff);
  half8 qf1 = *(const half8*)(Qw + qoff + 32);
#pragma unroll
  for (int e = 0; e < 8; e++) { qf0[e] *= SCALE; qf1[e] *= SCALE; }

  floatx4 o[4];
#pragma unroll
  for (int t = 0; t < 4; t++) o[t] = (floatx4)0.f;
  float mrow[4], lrow[4];
#pragma unroll
  for (int r = 0; r < 4; r++) { mrow[r] = NEG; lrow[r] = 0.f; }

  const int srow = tid >> 2;          // K staging: 0..63
  const int sc = (tid & 3) * 16;      // 0,16,32,48
  const int sp = tid & 31;            // V staging: s-pair 0..31
  const int h0 = (tid >> 5) * 8;      // 0..56
  unsigned int* vt32 = (unsigned int*)&vt_lds[0][0];  // [h][36] dwords

  for (int j = 0; j <= qt; j++) {
    __syncthreads();  // protect k_lds/vt_lds from previous iteration's readers
    {
      const size_t kbase = ((size_t)bb * 256 + j * 64 + srow) * 64 + sc;
      const half8* ksrc = (const half8*)(Kw + kbase);
      half8 ka = ksrc[0], kb = ksrc[1];
      *(half8*)&k_lds[srow][sc]     = ka;
      *(half8*)&k_lds[srow][sc + 8] = kb;
      // V transpose: pack s-pairs into dwords -> all 32 banks 2x (free)
      const _Float16* vsrc = Vw + ((size_t)bb * 256 + j * 64 + 2 * sp) * 64 + h0;
      half8 va = *(const half8*)vsrc;
      half8 vb = *(const half8*)(vsrc + 64);
#pragma unroll
      for (int e = 0; e < 8; e++) {
        union { _Float16 h[2]; unsigned int u; } pk;
        pk.h[0] = va[e]; pk.h[1] = vb[e];
        vt32[(h0 + e) * 36 + sp] = pk.u;
      }
    }
    __syncthreads();

    // S = (scaled Q) K^T : 16 q-rows x 64 s-cols per wave (already log2-domain)
    floatx4 sacc[4];
#pragma unroll
    for (int t = 0; t < 4; t++) sacc[t] = (floatx4)0.f;
#pragma unroll
    for (int t = 0; t < 4; t++) {
      half8 b0 = *(const half8*)&k_lds[t * 16 + l15][quad * 8];
      sacc[t] = MFMA16(qf0, b0, sacc[t]);
      half8 b1 = *(const half8*)&k_lds[t * 16 + l15][32 + quad * 8];
      sacc[t] = MFMA16(qf1, b1, sacc[t]);
    }

    float y[4][4];
#pragma unroll
    for (int t = 0; t < 4; t++)
#pragma unroll
      for (int r = 0; r < 4; r++) y[t][r] = sacc[t][r];
    if (j == qt) {
#pragma unroll
      for (int t = 0; t < 4; t++)
#pragma unroll
        for (int r = 0; r < 4; r++)
          if (t * 16 + l15 > wv * 16 + quad * 4 + r) y[t][r] = NEG;
    }

    // online softmax per q-row (reduce across the 16 lanes holding the row)
#pragma unroll
    for (int r = 0; r < 4; r++) {
      float mx = fmaxf(fmaxf(y[0][r], y[1][r]), fmaxf(y[2][r], y[3][r]));
#pragma unroll
      for (int off = 1; off < 16; off <<= 1) mx = fmaxf(mx, __shfl_xor(mx, off, 64));
      float mnew = fmaxf(mrow[r], mx);
      float al = exp2f(mrow[r] - mnew);
      mrow[r] = mnew;
      float rs = 0.f;
#pragma unroll
      for (int t = 0; t < 4; t++) {
        float p = exp2f(y[t][r] - mnew);
        y[t][r] = p;
        rs += p;
      }
#pragma unroll
      for (int off = 1; off < 16; off <<= 1) rs += __shfl_xor(rs, off, 64);
      lrow[r] = lrow[r] * al + rs;
      o[0][r] *= al; o[1][r] *= al; o[2][r] *= al; o[3][r] *= al;
    }

    // P: C/D layout -> LDS -> A layout. p_lds[wv] is wave-private: no barrier.
#pragma unroll
    for (int t = 0; t < 4; t++)
#pragma unroll
      for (int r = 0; r < 4; r++)
        p_lds[wv][quad * 4 + r][t * 16 + l15] = (_Float16)y[t][r];

    // O += P V
#pragma unroll
    for (int ss = 0; ss < 2; ss++) {
      half8 pa = *(const half8*)&p_lds[wv][l15][ss * 32 + quad * 8];
#pragma unroll
      for (int th = 0; th < 4; th++) {
        half8 vb = *(const half8*)&vt_lds[th * 16 + l15][ss * 32 + quad * 8];
        o[th] = MFMA16(pa, vb, o[th]);
      }
    }
  }

  // normalize + store fp32
#pragma unroll
  for (int th = 0; th < 4; th++)
#pragma unroll
    for (int r = 0; r < 4; r++) {
      int grow = qt * 64 + wv * 16 + quad * 4 + r;
      Out[((size_t)bb * 256 + grow) * 64 + th * 16 + l15] = o[th][r] / lrow[r];
    }
}

extern "C" void kernel_launch(void* const* d_in, const int* in_sizes, int n_in,
                              void* d_out, int out_size, void* d_ws, size_t ws_size,
                              hipStream_t stream) {
  const float* x  = (const float*)d_in[0];
  const float* y  = (const float*)d_in[1];
  const float* Wq = (const float*)d_in[2];
  const float* Wk = (const float*)d_in[3];
  const float* Wv = (const float*)d_in[4];
  float* out = (float*)d_out;

  _Float16* qw = (_Float16*)d_ws;
  _Float16* kw = qw + (size_t)65536 * 64;
  _Float16* vw = kw + (size_t)65536 * 64;
  _Float16* wpack = vw + (size_t)65536 * 64;  // 3 * 32768 halves

  pack_kernel<<<dim3(16, 3), 256, 0, stream>>>(Wq, Wk, Wv, wpack);
  proj_kernel<<<2048, 256, 0, stream>>>(x, y, wpack, qw, kw, vw);
  attn_kernel<<<dim3(4, 256), 256, 0, stream>>>(qw, kw, vw, out);
}